// Round 11
// baseline (403.031 us; speedup 1.0000x reference)
//
#include <hip/hip_runtime.h>
#include <hip/hip_bf16.h>

// Problem constants: N=50000, E=800000, G=512, L=3, D=128
#define D_FEAT 128
#define N_GRAPHS 512
#define N_LAYERS 3
#define POOL_DIM (N_LAYERS * D_FEAT)   // 384
#define N_CLASSES 10
#define BN_EPS 1e-5f
#define CAP 64                         // fixed bucket capacity; P(deg>64) ~ 2e-18
#define NBINS 8
#define SLABCAP 768                    // per (bin,block) slab; mean 390, 13.5 sigma
#define NSLICE 4                       // feature slices: 128 cols -> 4 x 32 cols (64B)

// LESSON (r7): gather is latency/issue-bound -> max occupancy + tiny footprint.
// LESSON (r3/r8): scatter regions written at <64B granularity by blocks on
// multiple XCDs get ~16x writeback amplification.
// LESSON (r10/r20): on gfx950 the __launch_bounds__ min-waves arg over-clamps
// VGPRs (r20: 32 VGPR -> spills -> 144MB scratch/dispatch). Plain bounds.
// LESSON (r11): never shrink a small kernel's grid below ~256 blocks.
// r17 WIN (304us): slice partition, persistent 2048-block grid (stable
// %8->XCD), uint4 register indices via shfl.
// r18 FAILED: degree-sort scattered streams. RULE: clamp every workspace-
// sourced loop bound in the consuming kernel.
// r19 FAILED: NT hints -> double HBM round trip on producer->consumer bufs.
// r21 NEUTRAL: depth-8 == depth-4; 32 waves/CU TLP covers ILP; agg CLOSED.
// r22/r23 WIN (294.7us): 32x32x16 MFMA layer (24 ds_read vs 36/GEMM). C/D:
// col=lane&31, row=(reg&3)+8*(reg>>2)+4*(lane>>5). K-packing cancels A<->B.
// r24 FAILED (+18.5us): B-frags-in-regs = uncoalesced 256B-stride W gather.
// RULE: register panels only pay when the load stays coalesced.
// r25 CALIBRATION: 16 no-ops -> +20.4us -> L ~= 1.3us/launch; 9 launches
// ~= 12us total. Kernels own ~283us; attribution agg vs layer unknown.
// r26 (this round): PER-KERNEL TIMING via internal reps. agg reps=2
// (idempotent), layer reps=3 (pooled atomics on last rep only; outh
// idempotent). asm memory clobber per rep blocks cross-rep CSE; reps is a
// host literal (poison-safe). Each dispatch now exceeds the 42us poison
// fills -> surfaces in top-5 WITH counters. dur ~= 294.7 + 3*agg + 6*layer.
// Pre-committed: agg>=30 -> reopen agg per its counters; agg<=20 &
// layer>=20 -> layer staging (global_load_lds); both small -> front-end.

typedef __attribute__((ext_vector_type(8))) short bf16x8;
typedef __attribute__((ext_vector_type(8))) unsigned short ushort8;
typedef __attribute__((ext_vector_type(16))) float f32x16;

__device__ __forceinline__ unsigned short f2bf(float f) {
    unsigned u = __builtin_bit_cast(unsigned, f);
    u += 0x7FFFu + ((u >> 16) & 1u);          // round-to-nearest-even
    return (unsigned short)(u >> 16);
}
__device__ __forceinline__ float bf2f(unsigned short h) {
    unsigned u = ((unsigned)h) << 16;
    return __builtin_bit_cast(float, u);
}
__device__ __forceinline__ float bf_lo(unsigned u) {
    return __builtin_bit_cast(float, u << 16);
}
__device__ __forceinline__ float bf_hi(unsigned u) {
    return __builtin_bit_cast(float, u & 0xffff0000u);
}

// ---------------------------------------------------------------------------
// Merged setup: cvt_x (slice-major) | cvt_w(LDS-transpose tiles) | prep |
// zero cursor | zero pooled | BIN (radix partition into per-(bin,block)
// private slabs).
// ---------------------------------------------------------------------------
__global__ __launch_bounds__(256) void setup_kernel(
        const float* __restrict__ x, unsigned short* __restrict__ xb,
        const float* __restrict__ W1, const float* __restrict__ W2,
        unsigned short* __restrict__ Wt,
        const float* __restrict__ b1, const float* __restrict__ gamma,
        const float* __restrict__ beta, const float* __restrict__ rm,
        const float* __restrict__ rv, const float* __restrict__ b2,
        float* __restrict__ ea, float* __restrict__ eb,
        int* __restrict__ cursor, float* __restrict__ pooled,
        const int* __restrict__ ei, int2* __restrict__ pairs,
        int* __restrict__ cnts, int E,
        int N, int n4, int B0, int B1, int B2, int B3, int B4) {
    int b = blockIdx.x, tid = threadIdx.x;
    if (b < B0) {                                     // cvt_x: fp32 -> bf16, slice-major
        int i = b * 256 + tid;
        if (i < n4) {
            float4 v = ((const float4*)x)[i];
            ushort4 o;
            o.x = f2bf(v.x); o.y = f2bf(v.y); o.z = f2bf(v.z); o.w = f2bf(v.w);
            int node = i >> 5;            // 32 ushort4-groups per 128-col row
            int c4 = i & 31;              // col = c4*4
            int sl = c4 >> 3;             // slice = col>>5
            int off = c4 & 7;             // ushort4 slot within 32-col slice
            ((ushort4*)xb)[((size_t)sl * N + node) * 8 + off] = o;
        }
    } else if (b < B1) {                              // cvt_w: coalesced transpose
        __shared__ float tile[64][65];
        int t = b - B0;                               // 0..23
        int slot = t >> 2;                            // 6 slots
        int r0 = ((t >> 1) & 1) * 64;                 // k-block in W rows
        int c0 = (t & 1) * 64;                        // n-block in W cols
        int l = slot >> 1;
        const float* W = (slot & 1) ? W2 : W1;
        const float* Wb = W + (size_t)l * D_FEAT * D_FEAT;
        int rr = tid >> 2, cc4 = (tid & 3) * 16;
        #pragma unroll
        for (int j = 0; j < 16; ++j)
            tile[rr][cc4 + j] = Wb[(size_t)(r0 + rr) * D_FEAT + c0 + cc4 + j];
        __syncthreads();
        int nn = tid >> 2, kk4 = (tid & 3) * 16;
        unsigned short* Wo = Wt + (size_t)slot * D_FEAT * D_FEAT;
        #pragma unroll
        for (int j = 0; j < 16; ++j)
            Wo[(size_t)(c0 + nn) * D_FEAT + r0 + kk4 + j] = f2bf(tile[kk4 + j][nn]);
    } else if (b < B2) {                              // prep: fold BN+bias
        int i = (b - B1) * 256 + tid;
        if (i < N_LAYERS * D_FEAT) {
            int l = i >> 7, c = i & 127;
            float s = gamma[i] * rsqrtf(rv[i] + BN_EPS);
            ea[(2 * l) * D_FEAT + c] = s;
            eb[(2 * l) * D_FEAT + c] = (b1[i] - rm[i]) * s + beta[i];
            ea[(2 * l + 1) * D_FEAT + c] = 1.0f;
            eb[(2 * l + 1) * D_FEAT + c] = b2[i];
        }
    } else if (b < B3) {                              // zero cursor
        int i = (b - B2) * 256 + tid;
        if (i < N) cursor[i] = 0;
    } else if (b < B4) {                              // zero pooled
        int i = (b - B3) * 256 + tid;
        if (i < N_GRAPHS * POOL_DIM) pooled[i] = 0.f;
    } else {                                          // bin: radix partition
        __shared__ int loc[NBINS];
        int bb = b - B4;                              // 0..255
        int per = (E + 255) / 256;
        int e0 = bb * per;
        int e1 = e0 + per; if (e1 > E) e1 = E;
        int span = (N + NBINS - 1) / NBINS;
        if (tid < NBINS) loc[tid] = 0;
        __syncthreads();
        for (int e = e0 + tid; e < e1; e += 256) {
            int dst = ei[E + e];
            int src = ei[e];
            int bin = dst / span;
            int p = atomicAdd(&loc[bin], 1);
            if (p < SLABCAP)
                pairs[((size_t)(bin * 256 + bb)) * SLABCAP + p] = make_int2(src, dst);
        }
        __syncthreads();
        if (tid < NBINS)
            cnts[tid * 256 + bb] = loc[tid];
    }
}

// ---------------------------------------------------------------------------
// Fill: blockIdx%8 = dst-range = XCD (CP round-robin): cursor atomics +
// bucket scatter stay in one XCD's L2. Dense slab reads. bucket is ushort.
// ---------------------------------------------------------------------------
__global__ __launch_bounds__(256) void fill_v3(const int2* __restrict__ pairs,
                                               const int* __restrict__ cnts,
                                               int* __restrict__ cursor,
                                               unsigned short* __restrict__ bucket) {
    int r = blockIdx.x & 7;
    int chunk = blockIdx.x >> 3;              // 0..63
    #pragma unroll
    for (int s = 0; s < 4; ++s) {
        int blk = chunk * 4 + s;              // 0..255
        int cnt = cnts[r * 256 + blk];
        if (cnt > SLABCAP) cnt = SLABCAP;
        const int2* slab = pairs + (size_t)(r * 256 + blk) * SLABCAP;
        for (int p = threadIdx.x; p < cnt; p += 256) {
            int2 pr = slab[p];
            int pos = atomicAdd(&cursor[pr.y], 1);
            if (pos < CAP)
                bucket[(size_t)pr.y * CAP + pos] = (unsigned short)pr.x;
        }
    }
}

// ---------------------------------------------------------------------------
// Slice-partitioned aggregation (r17 structure) + r26 reps instrumentation:
// reps is a HOST LITERAL (2); all work is idempotent (same ys rewritten).
// asm memory clobber per rep prevents cross-rep load CSE. Dispatch duration
// = reps * agg_time -> exceeds 42us poison fills -> visible in top-5.
// ---------------------------------------------------------------------------
__global__ __launch_bounds__(256) void agg_slice(
        const unsigned short* __restrict__ hs,      // [NSLICE][N][32] bf16
        const int* __restrict__ deg,
        const unsigned short* __restrict__ bucket,  // [N][CAP] ushort
        unsigned short* __restrict__ ys,            // [NSLICE][N][32] bf16
        int n, int nchunks, int reps) {
    int xcd = blockIdx.x & 7;
    int s = xcd >> 1;                            // slice for this XCD pair
    int worker = (blockIdx.x >> 3) * 2 + (xcd & 1);   // 0..511 within slice
    int wave = threadIdx.x >> 6, lane = threadIdx.x & 63;
    int grp = lane >> 2, sub = lane & 3;         // 16 nodes/wave, 4 lanes/node
    const uint4* h4 = (const uint4*)hs;
    size_t sbase = (size_t)s * n * 4;            // uint4 units per slice

    for (int rep = 0; rep < reps; ++rep) {
    asm volatile("" ::: "memory");               // no cross-rep CSE
    for (int chunk = worker; chunk < nchunks; chunk += 512) {
        int n0 = chunk * 64 + wave * 16 + grp;
        bool valid = n0 < n;
        int node = valid ? n0 : 0;
        int d = valid ? deg[node] : 0;
        if (d > CAP) d = CAP;                    // poison-replay safe clamp
        const unsigned short* brow = bucket + (size_t)node * CAP;

        // coalesced index prefetch: lane sub holds entries sub*8..sub*8+7
        uint4 iv = *(const uint4*)&brow[sub * 8];

        // self slice (issue early; consumed at the end)
        uint4 sv = h4[sbase + (size_t)node * 4 + sub];

        // wave-wide max degree (uniform loop bound; per-group predication)
        int dmax = d;
        dmax = max(dmax, __shfl_xor(dmax, 4));
        dmax = max(dmax, __shfl_xor(dmax, 8));
        dmax = max(dmax, __shfl_xor(dmax, 16));
        dmax = max(dmax, __shfl_xor(dmax, 32));

        float acc[8] = {0.f,0.f,0.f,0.f,0.f,0.f,0.f,0.f};

        int dcap = dmax < 32 ? dmax : 32;        // prefix held in registers
        for (int t = 0; t < dcap; t += 8) {
            int src = (grp << 2) + (t >> 3);     // lane holding entries t..t+7
            unsigned q0 = (unsigned)__shfl((int)iv.x, src);
            unsigned q1 = (unsigned)__shfl((int)iv.y, src);
            unsigned q2 = (unsigned)__shfl((int)iv.z, src);
            unsigned q3 = (unsigned)__shfl((int)iv.w, src);
            int id[8];
            id[0] = (int)(q0 & 0xffffu); id[1] = (int)(q0 >> 16);
            id[2] = (int)(q1 & 0xffffu); id[3] = (int)(q1 >> 16);
            id[4] = (int)(q2 & 0xffffu); id[5] = (int)(q2 >> 16);
            id[6] = (int)(q3 & 0xffffu); id[7] = (int)(q3 >> 16);
            uint4 w[8];
            #pragma unroll
            for (int u = 0; u < 8; ++u) {
                w[u] = make_uint4(0u, 0u, 0u, 0u);
                if (t + u < d)
                    w[u] = h4[sbase + (size_t)id[u] * 4 + sub];
            }
            #pragma unroll
            for (int u = 0; u < 8; ++u) {
                uint4 v = w[u];
                acc[0] += bf_lo(v.x); acc[1] += bf_hi(v.x);
                acc[2] += bf_lo(v.y); acc[3] += bf_hi(v.y);
                acc[4] += bf_lo(v.z); acc[5] += bf_hi(v.z);
                acc[6] += bf_lo(v.w); acc[7] += bf_hi(v.w);
            }
        }
        // rare tail: deg > 32 (P ~ 2e-4 per node)
        for (int e = 32; e < d; ++e) {
            int idx = (int)brow[e];
            uint4 v = h4[sbase + (size_t)idx * 4 + sub];
            acc[0] += bf_lo(v.x); acc[1] += bf_hi(v.x);
            acc[2] += bf_lo(v.y); acc[3] += bf_hi(v.y);
            acc[4] += bf_lo(v.z); acc[5] += bf_hi(v.z);
            acc[6] += bf_lo(v.w); acc[7] += bf_hi(v.w);
        }

        // add self
        acc[0] += bf_lo(sv.x); acc[1] += bf_hi(sv.x);
        acc[2] += bf_lo(sv.y); acc[3] += bf_hi(sv.y);
        acc[4] += bf_lo(sv.z); acc[5] += bf_hi(sv.z);
        acc[6] += bf_lo(sv.w); acc[7] += bf_hi(sv.w);

        if (valid) {
            uint4 o;
            o.x = (unsigned)f2bf(acc[0]) | ((unsigned)f2bf(acc[1]) << 16);
            o.y = (unsigned)f2bf(acc[2]) | ((unsigned)f2bf(acc[3]) << 16);
            o.z = (unsigned)f2bf(acc[4]) | ((unsigned)f2bf(acc[5]) << 16);
            o.w = (unsigned)f2bf(acc[6]) | ((unsigned)f2bf(acc[7]) << 16);
            ((uint4*)ys)[sbase + (size_t)node * 4 + sub] = o;   // 1KB/wave contiguous
        }
    }
    }
}

// ---------------------------------------------------------------------------
// Fused layer GEMM v2 (r23 structure) + r26 reps instrumentation: reps is a
// HOST LITERAL (3); pooled atomics run ONLY on the last rep (exactly one
// contribution); outh rewrites are idempotent. Barrier at rep start guards
// cross-rep As reuse. Dispatch duration = reps * layer_time -> top-5.
// ---------------------------------------------------------------------------
__global__ __launch_bounds__(256) void layer_fused(const unsigned short* __restrict__ A,
                                                   const unsigned short* __restrict__ Wt1,
                                                   const unsigned short* __restrict__ Wt2,
                                                   const float* __restrict__ ea1,
                                                   const float* __restrict__ eb1,
                                                   const float* __restrict__ ea2,
                                                   const float* __restrict__ eb2,
                                                   const int* __restrict__ batch,
                                                   float* __restrict__ pooled, int loff,
                                                   unsigned short* __restrict__ outh, int n,
                                                   int reps) {
    __shared__ unsigned short As[64][136];
    __shared__ unsigned short Ws[128][136];
    __shared__ int bsh[64];
    int tid = threadIdx.x;
    int row0 = blockIdx.x * 64;
    int wave = tid >> 6, lane = tid & 63;
    int stripe = wave & 1;                 // 32-row stripe within the tile
    int nhalf = wave >> 1;                 // 64-col half
    int lc = lane & 31;                    // A-row / B-col within 32-tile
    int lh = lane >> 5;                    // k-half / C-row offset

    for (int rep = 0; rep < reps; ++rep) {
    asm volatile("" ::: "memory");         // no cross-rep CSE
    if (rep) __syncthreads();              // guard As against lagging waves

    #pragma unroll
    for (int i = 0; i < 4; ++i) {
        int idx = tid + i * 256;
        int r = idx >> 4, c = (idx & 15) * 8;
        int sl = c >> 5, off = c & 31;
        ushort8 v = (ushort8)0;
        if (row0 + r < n)
            v = *(const ushort8*)&A[((size_t)sl * n + (row0 + r)) * 32 + off];
        *(ushort8*)&As[r][c] = v;
    }
    #pragma unroll
    for (int i = 0; i < 8; ++i) {
        int idx = tid + i * 256;
        int r = idx >> 4, c = (idx & 15) * 8;
        *(ushort8*)&Ws[r][c] = *(const ushort8*)&Wt1[(size_t)r * D_FEAT + c];
    }

    ushort8 w2reg[8];
    #pragma unroll
    for (int i = 0; i < 8; ++i) {
        int idx = tid + i * 256;
        int r = idx >> 4, c = (idx & 15) * 8;
        w2reg[i] = *(const ushort8*)&Wt2[(size_t)r * D_FEAT + c];
    }

    if (tid < 64)
        bsh[tid] = (row0 + tid < n) ? batch[row0 + tid] : -1;
    __syncthreads();

    // ---- GEMM 1 (32x32x16) ----
    f32x16 acc[2] = {};
    #pragma unroll
    for (int t = 0; t < 8; ++t) {
        bf16x8 a = *(const bf16x8*)&As[stripe * 32 + lc][t * 16 + lh * 8];
        #pragma unroll
        for (int nt = 0; nt < 2; ++nt) {
            bf16x8 b = *(const bf16x8*)&Ws[nhalf * 64 + nt * 32 + lc][t * 16 + lh * 8];
            acc[nt] = __builtin_amdgcn_mfma_f32_32x32x16_bf16(a, b, acc[nt], 0, 0, 0);
        }
    }
    __syncthreads();

    // epilogue 1 -> z (bf16) into As; restore Ws = Wt2 from registers
    #pragma unroll
    for (int nt = 0; nt < 2; ++nt) {
        int col = nhalf * 64 + nt * 32 + lc;
        float al = ea1[col], be = eb1[col];
        #pragma unroll
        for (int reg = 0; reg < 16; ++reg) {
            int rr = (reg & 3) + 8 * (reg >> 2) + 4 * lh;
            float v = fmaxf(fmaf(acc[nt][reg], al, be), 0.f);
            As[stripe * 32 + rr][col] = f2bf(v);
        }
    }
    #pragma unroll
    for (int i = 0; i < 8; ++i) {
        int idx = tid + i * 256;
        int r = idx >> 4, c = (idx & 15) * 8;
        *(ushort8*)&Ws[r][c] = w2reg[i];
    }
    __syncthreads();

    // ---- GEMM 2 (32x32x16) ----
    f32x16 acc2[2] = {};
    #pragma unroll
    for (int t = 0; t < 8; ++t) {
        bf16x8 a = *(const bf16x8*)&As[stripe * 32 + lc][t * 16 + lh * 8];
        #pragma unroll
        for (int nt = 0; nt < 2; ++nt) {
            bf16x8 b = *(const bf16x8*)&Ws[nhalf * 64 + nt * 32 + lc][t * 16 + lh * 8];
            acc2[nt] = __builtin_amdgcn_mfma_f32_32x32x16_bf16(a, b, acc2[nt], 0, 0, 0);
        }
    }

    // per-lane graph ids for its 16 rows (depends only on lh, reg)
    int bq[16];
    #pragma unroll
    for (int reg = 0; reg < 16; ++reg)
        bq[reg] = bsh[stripe * 32 + (reg & 3) + 8 * (reg >> 2) + 4 * lh];

    // epilogue 2: bf16-rounded h once; global write + pooling values
    float vv[2][16];
    #pragma unroll
    for (int nt = 0; nt < 2; ++nt) {
        int col = nhalf * 64 + nt * 32 + lc;
        float al = ea2[col], be = eb2[col];
        int sl = col >> 5, off = col & 31;
        #pragma unroll
        for (int reg = 0; reg < 16; ++reg) {
            int rr = (reg & 3) + 8 * (reg >> 2) + 4 * lh;
            unsigned short hb = f2bf(fmaxf(fmaf(acc2[nt][reg], al, be), 0.f));
            vv[nt][reg] = bf2f(hb);
            if (outh) {
                int grow = row0 + stripe * 32 + rr;
                if (grow < n)
                    outh[((size_t)sl * n + grow) * 32 + off] = hb;
            }
        }
    }

    if (rep == reps - 1) {
        // wave pooling: rows span contiguous graphs [gmn,gmx] (batch sorted)
        int gmn = 0x7fffffff, gmx = -1;
        #pragma unroll
        for (int reg = 0; reg < 16; ++reg) {
            int bb = bq[reg];
            if (bb >= 0) {
                gmn = bb < gmn ? bb : gmn;
                gmx = bb > gmx ? bb : gmx;
            }
        }
        {
            int t;
            t = __shfl_xor(gmn, 32); gmn = t < gmn ? t : gmn;
            t = __shfl_xor(gmx, 32); gmx = t > gmx ? t : gmx;
        }
        for (int seg = gmn; seg <= gmx; ++seg) {
            #pragma unroll
            for (int nt = 0; nt < 2; ++nt) {
                float s = 0.f;
                #pragma unroll
                for (int reg = 0; reg < 16; ++reg)
                    if (bq[reg] == seg) s += vv[nt][reg];
                s += __shfl_xor(s, 32);
                if (lh == 0 && s != 0.f)
                    atomicAdd(&pooled[(size_t)seg * POOL_DIM + loff +
                                      nhalf * 64 + nt * 32 + lc], s);
            }
        }
    }
    }
}

// ---------------------------------------------------------------------------
// Fused MLP head: 128 blocks x 384 threads, 4 graphs/block. fc1 (coalesced
// W1, graphs in registers, k ascending) -> f1 in LDS -> fc2 by threads 0..39.
// ---------------------------------------------------------------------------
__global__ __launch_bounds__(384) void head_kernel(const float* __restrict__ pooled,
                                                   const float* __restrict__ W1,
                                                   const float* __restrict__ b1v,
                                                   const float* __restrict__ W2,
                                                   const float* __restrict__ b2v,
                                                   float* __restrict__ out) {
    __shared__ float f1[4][POOL_DIM];
    int j = threadIdx.x;                   // 0..383
    int g0 = blockIdx.x * 4;
    const float* pr = pooled + (size_t)g0 * POOL_DIM;
    float bb = b1v[j];
    float s0 = bb, s1 = bb, s2 = bb, s3 = bb;
    for (int k0 = 0; k0 < POOL_DIM; k0 += 8) {
        float w[8];
        #pragma unroll
        for (int i = 0; i < 8; ++i)
            w[i] = W1[(size_t)(k0 + i) * POOL_DIM + j];
        #pragma unroll
        for (int i = 0; i < 8; ++i) {
            int k = k0 + i;
            s0 = fmaf(pr[k],                w[i], s0);
            s1 = fmaf(pr[POOL_DIM + k],     w[i], s1);
            s2 = fmaf(pr[2 * POOL_DIM + k], w[i], s2);
            s3 = fmaf(pr[3 * POOL_DIM + k], w[i], s3);
        }
    }
    f1[0][j] = fmaxf(s0, 0.f);
    f1[1][j] = fmaxf(s1, 0.f);
    f1[2][j] = fmaxf(s2, 0.f);
    f1[3][j] = fmaxf(s3, 0.f);
    __syncthreads();
    if (j < 4 * N_CLASSES) {
        int g = j / N_CLASSES, c = j % N_CLASSES;
        float s = b2v[c];
        for (int k = 0; k < POOL_DIM; ++k)
            s = fmaf(f1[g][k], W2[(size_t)k * N_CLASSES + c], s);
        out[(size_t)(g0 + g) * N_CLASSES + c] = s;
    }
}

// ---------------------------------------------------------------------------
extern "C" void kernel_launch(void* const* d_in, const int* in_sizes, int n_in,
                              void* d_out, int out_size, void* d_ws, size_t ws_size,
                              hipStream_t stream) {
    const float* x      = (const float*)d_in[0];
    const int*   ei     = (const int*)  d_in[1];
    const int*   batch  = (const int*)  d_in[2];
    const float* W1     = (const float*)d_in[3];
    const float* b1     = (const float*)d_in[4];
    const float* gamma  = (const float*)d_in[5];
    const float* beta   = (const float*)d_in[6];
    const float* rm     = (const float*)d_in[7];
    const float* rv     = (const float*)d_in[8];
    const float* W2     = (const float*)d_in[9];
    const float* b2     = (const float*)d_in[10];
    const float* lin1W  = (const float*)d_in[11];
    const float* lin1b  = (const float*)d_in[12];
    const float* lin2W  = (const float*)d_in[13];
    const float* lin2b  = (const float*)d_in[14];
    float* out = (float*)d_out;

    const int N = in_sizes[0] / D_FEAT;   // 50000
    const int E = in_sizes[1] / 2;        // 800000

    char* ws = (char*)d_ws;
    auto carve = [&](size_t bytes) {
        char* p = ws;
        ws += (bytes + 255) & ~(size_t)255;
        return p;
    };
    int*   cursor    = (int*)  carve((size_t)N * 4);
    int*   cnts      = (int*)  carve((size_t)NBINS * 256 * 4);
    unsigned short* bucket = (unsigned short*)carve((size_t)N * CAP * 2);
    int2*  pairs     = (int2*) carve((size_t)NBINS * 256 * SLABCAP * 8);
    float* ea        = (float*)carve((size_t)2 * N_LAYERS * D_FEAT * 4);
    float* eb        = (float*)carve((size_t)2 * N_LAYERS * D_FEAT * 4);
    unsigned short* Wt   = (unsigned short*)carve((size_t)2 * N_LAYERS * D_FEAT * D_FEAT * 2);
    unsigned short* xb   = (unsigned short*)carve((size_t)N * D_FEAT * 2);
    unsigned short* ybuf = (unsigned short*)carve((size_t)N * D_FEAT * 2);
    unsigned short* hbuf = (unsigned short*)carve((size_t)N * D_FEAT * 2);
    float* pooled    = (float*)carve((size_t)N_GRAPHS * POOL_DIM * 4);

    // merged setup grid layout
    const int n4 = N * D_FEAT / 4;
    const int B0 = (n4 + 255) / 256;                            // cvt_x
    const int B1 = B0 + 24;                                     // cvt_w: 6 slots x 4 tiles
    const int B2 = B1 + 2;                                      // prep
    const int B3 = B2 + (N + 255) / 256;                        // cursor zero
    const int B4 = B3 + (N_GRAPHS * POOL_DIM + 255) / 256;      // pooled zero
    const int B5 = B4 + 256;                                    // bin

    setup_kernel<<<B5, 256, 0, stream>>>(x, xb, W1, W2, Wt, b1, gamma, beta,
                                         rm, rv, b2, ea, eb, cursor, pooled,
                                         ei, pairs, cnts, E,
                                         N, n4, B0, B1, B2, B3, B4);
    fill_v3<<<8 * 64, 256, 0, stream>>>(pairs, cnts, cursor, bucket);

    const int nchunks = (N + 63) / 64;              // 64 nodes per chunk

    const unsigned short* hprev = xb;
    for (int l = 0; l < N_LAYERS; ++l) {
        agg_slice<<<2048, 256, 0, stream>>>(hprev, cursor, bucket, ybuf,
                                            N, nchunks, /*reps=*/2);
        unsigned short* outh = (l == N_LAYERS - 1) ? nullptr : hbuf;
        layer_fused<<<(N + 63) / 64, 256, 0, stream>>>(ybuf,
                      Wt + (size_t)(2 * l) * D_FEAT * D_FEAT,
                      Wt + (size_t)(2 * l + 1) * D_FEAT * D_FEAT,
                      ea + (size_t)(2 * l) * D_FEAT,
                      eb + (size_t)(2 * l) * D_FEAT,
                      ea + (size_t)(2 * l + 1) * D_FEAT,
                      eb + (size_t)(2 * l + 1) * D_FEAT,
                      batch, pooled, l * D_FEAT, outh, N, /*reps=*/3);
        hprev = hbuf;
    }
    head_kernel<<<N_GRAPHS / 4, 384, 0, stream>>>(pooled, lin1W, lin1b, lin2W, lin2b, out);
}

// Round 12
// 293.977 us; speedup vs baseline: 1.3710x; 1.3710x over previous
//
#include <hip/hip_runtime.h>
#include <hip/hip_bf16.h>

// Problem constants: N=50000, E=800000, G=512, L=3, D=128
#define D_FEAT 128
#define N_GRAPHS 512
#define N_LAYERS 3
#define POOL_DIM (N_LAYERS * D_FEAT)   // 384
#define N_CLASSES 10
#define BN_EPS 1e-5f
#define CAP 64                         // fixed bucket capacity; P(deg>64) ~ 2e-18
#define NBINS 8
#define SLABCAP 768                    // per (bin,block) slab; mean 390, 13.5 sigma
#define NSLICE 4                       // feature slices: 128 cols -> 4 x 32 cols (64B)

// LESSON (r7): gather is latency/issue-bound -> max occupancy + tiny footprint.
// LESSON (r3/r8): scatter regions written at <64B granularity by blocks on
// multiple XCDs get ~16x writeback amplification.
// LESSON (r10/r20): on gfx950 the __launch_bounds__ min-waves arg over-clamps
// VGPRs (r20: 32 VGPR -> spills -> 144MB scratch/dispatch). Plain bounds.
// LESSON (r11): never shrink a small kernel's grid below ~256 blocks.
// r17 WIN: slice partition, persistent 2048-block grid (stable %8->XCD).
// r18 FAILED: degree-sort scattered streams. RULE: clamp every workspace-
// sourced loop bound in the consuming kernel.
// r19 FAILED: NT hints -> double HBM round trip on producer->consumer bufs.
// r21 NEUTRAL: depth-8 == depth-4; TLP covers ILP.
// r22/r23 WIN (294.7us): 32x32x16 MFMA layer. C/D: col=lane&31,
// row=(reg&3)+8*(reg>>2)+4*(lane>>5).
// r24 FAILED: B-frags-in-regs = uncoalesced 256B-stride W gather.
// r25/r26 MEASURED: launch L~=1.3us (9 launches ~12us). agg=23.5us/pass,
// layer=6.3us/pass, head~3, setup/fill~8 -> OUR work ~110us; remaining
// ~185us is harness-timed poison fills (4-5 x 42us, fixed). agg counters:
// FETCH=compulsory (slice-pinning perfect), VALUBusy~50%, rest waitcnt.
// agg VALU/gather ~27: 16 unpack-add (irreducible) + ~10 addressing/pred.
// r27 (this round): cut the addressing/pred VALU. (1) 32-bit saddr: uniform
// h4s base + off=id*4+sub (fits 12.8MB) -> global_load v,voff,s[base], one
// v_lshl_add_u32, no 64-bit chain. (2) zero-row predication: 64B zeroed row
// appended to xb/hbuf (zeroed in setup); masked gathers redirect off there
// (1 cndmask), accumulate unconditional -> no branches, no zero-init movs.
// Predict agg 23.5 -> ~19-20 -> total ~282-288. Flat -> ROOFLINE next.

typedef __attribute__((ext_vector_type(8))) short bf16x8;
typedef __attribute__((ext_vector_type(8))) unsigned short ushort8;
typedef __attribute__((ext_vector_type(16))) float f32x16;

__device__ __forceinline__ unsigned short f2bf(float f) {
    unsigned u = __builtin_bit_cast(unsigned, f);
    u += 0x7FFFu + ((u >> 16) & 1u);          // round-to-nearest-even
    return (unsigned short)(u >> 16);
}
__device__ __forceinline__ float bf2f(unsigned short h) {
    unsigned u = ((unsigned)h) << 16;
    return __builtin_bit_cast(float, u);
}
__device__ __forceinline__ float bf_lo(unsigned u) {
    return __builtin_bit_cast(float, u << 16);
}
__device__ __forceinline__ float bf_hi(unsigned u) {
    return __builtin_bit_cast(float, u & 0xffff0000u);
}

// ---------------------------------------------------------------------------
// Merged setup: cvt_x (slice-major) | cvt_w(LDS-transpose tiles) | prep
// (+ zero the 64B gather-null tails of xb and hbuf) | zero cursor | zero
// pooled | BIN (radix partition into per-(bin,block) private slabs).
// ---------------------------------------------------------------------------
__global__ __launch_bounds__(256) void setup_kernel(
        const float* __restrict__ x, unsigned short* __restrict__ xb,
        unsigned short* __restrict__ hb,
        const float* __restrict__ W1, const float* __restrict__ W2,
        unsigned short* __restrict__ Wt,
        const float* __restrict__ b1, const float* __restrict__ gamma,
        const float* __restrict__ beta, const float* __restrict__ rm,
        const float* __restrict__ rv, const float* __restrict__ b2,
        float* __restrict__ ea, float* __restrict__ eb,
        int* __restrict__ cursor, float* __restrict__ pooled,
        const int* __restrict__ ei, int2* __restrict__ pairs,
        int* __restrict__ cnts, int E,
        int N, int n4, int B0, int B1, int B2, int B3, int B4) {
    int b = blockIdx.x, tid = threadIdx.x;
    if (b < B0) {                                     // cvt_x: fp32 -> bf16, slice-major
        int i = b * 256 + tid;
        if (i < n4) {
            float4 v = ((const float4*)x)[i];
            ushort4 o;
            o.x = f2bf(v.x); o.y = f2bf(v.y); o.z = f2bf(v.z); o.w = f2bf(v.w);
            int node = i >> 5;            // 32 ushort4-groups per 128-col row
            int c4 = i & 31;              // col = c4*4
            int sl = c4 >> 3;             // slice = col>>5
            int off = c4 & 7;             // ushort4 slot within 32-col slice
            ((ushort4*)xb)[((size_t)sl * N + node) * 8 + off] = o;
        }
    } else if (b < B1) {                              // cvt_w: coalesced transpose
        __shared__ float tile[64][65];
        int t = b - B0;                               // 0..23
        int slot = t >> 2;                            // 6 slots
        int r0 = ((t >> 1) & 1) * 64;                 // k-block in W rows
        int c0 = (t & 1) * 64;                        // n-block in W cols
        int l = slot >> 1;
        const float* W = (slot & 1) ? W2 : W1;
        const float* Wb = W + (size_t)l * D_FEAT * D_FEAT;
        int rr = tid >> 2, cc4 = (tid & 3) * 16;
        #pragma unroll
        for (int j = 0; j < 16; ++j)
            tile[rr][cc4 + j] = Wb[(size_t)(r0 + rr) * D_FEAT + c0 + cc4 + j];
        __syncthreads();
        int nn = tid >> 2, kk4 = (tid & 3) * 16;
        unsigned short* Wo = Wt + (size_t)slot * D_FEAT * D_FEAT;
        #pragma unroll
        for (int j = 0; j < 16; ++j)
            Wo[(size_t)(c0 + nn) * D_FEAT + r0 + kk4 + j] = f2bf(tile[kk4 + j][nn]);
    } else if (b < B2) {                              // prep: fold BN+bias (+zero tails)
        int i = (b - B1) * 256 + tid;
        if (i < N_LAYERS * D_FEAT) {
            int l = i >> 7, c = i & 127;
            float s = gamma[i] * rsqrtf(rv[i] + BN_EPS);
            ea[(2 * l) * D_FEAT + c] = s;
            eb[(2 * l) * D_FEAT + c] = (b1[i] - rm[i]) * s + beta[i];
            ea[(2 * l + 1) * D_FEAT + c] = 1.0f;
            eb[(2 * l + 1) * D_FEAT + c] = b2[i];
        }
        if (b == B1 + 1) {                            // zero 64B gather-null rows
            if (tid >= 128 && tid < 160)
                xb[(size_t)N * D_FEAT + (tid - 128)] = 0;
            if (tid >= 160 && tid < 192)
                hb[(size_t)N * D_FEAT + (tid - 160)] = 0;
        }
    } else if (b < B3) {                              // zero cursor
        int i = (b - B2) * 256 + tid;
        if (i < N) cursor[i] = 0;
    } else if (b < B4) {                              // zero pooled
        int i = (b - B3) * 256 + tid;
        if (i < N_GRAPHS * POOL_DIM) pooled[i] = 0.f;
    } else {                                          // bin: radix partition
        __shared__ int loc[NBINS];
        int bb = b - B4;                              // 0..255
        int per = (E + 255) / 256;
        int e0 = bb * per;
        int e1 = e0 + per; if (e1 > E) e1 = E;
        int span = (N + NBINS - 1) / NBINS;
        if (tid < NBINS) loc[tid] = 0;
        __syncthreads();
        for (int e = e0 + tid; e < e1; e += 256) {
            int dst = ei[E + e];
            int src = ei[e];
            int bin = dst / span;
            int p = atomicAdd(&loc[bin], 1);
            if (p < SLABCAP)
                pairs[((size_t)(bin * 256 + bb)) * SLABCAP + p] = make_int2(src, dst);
        }
        __syncthreads();
        if (tid < NBINS)
            cnts[tid * 256 + bb] = loc[tid];
    }
}

// ---------------------------------------------------------------------------
// Fill: blockIdx%8 = dst-range = XCD (CP round-robin): cursor atomics +
// bucket scatter stay in one XCD's L2. Dense slab reads. bucket is ushort.
// ---------------------------------------------------------------------------
__global__ __launch_bounds__(256) void fill_v3(const int2* __restrict__ pairs,
                                               const int* __restrict__ cnts,
                                               int* __restrict__ cursor,
                                               unsigned short* __restrict__ bucket) {
    int r = blockIdx.x & 7;
    int chunk = blockIdx.x >> 3;              // 0..63
    #pragma unroll
    for (int s = 0; s < 4; ++s) {
        int blk = chunk * 4 + s;              // 0..255
        int cnt = cnts[r * 256 + blk];
        if (cnt > SLABCAP) cnt = SLABCAP;
        const int2* slab = pairs + (size_t)(r * 256 + blk) * SLABCAP;
        for (int p = threadIdx.x; p < cnt; p += 256) {
            int2 pr = slab[p];
            int pos = atomicAdd(&cursor[pr.y], 1);
            if (pos < CAP)
                bucket[(size_t)pr.y * CAP + pos] = (unsigned short)pr.x;
        }
    }
}

// ---------------------------------------------------------------------------
// Slice-partitioned aggregation v6 (r27): saddr addressing + zero-row
// predication. h is slice-major [NSLICE][N][32] bf16 with one zeroed 64B
// row appended at uint4 index NSLICE*n*4. h4s = uniform base for this
// slice -> 32-bit offsets -> global_load v,voff,s[base] (no 64-bit chain).
// Masked gathers redirect off to the zero row (L1-hot) and accumulate
// UNCONDITIONALLY (adds 0) -> no branches, no zero-init movs.
// Persistent 2048-block grid; wave = 16 nodes, 4 lanes/node; indices via
// one coalesced uint4 + shfl. d clamped in-kernel (poison-replay safe).
// ---------------------------------------------------------------------------
__global__ __launch_bounds__(256) void agg_slice(
        const unsigned short* __restrict__ hs,      // [NSLICE][N][32] bf16 + 64B zero
        const int* __restrict__ deg,
        const unsigned short* __restrict__ bucket,  // [N][CAP] ushort
        unsigned short* __restrict__ ys,            // [NSLICE][N][32] bf16
        int n, int nchunks) {
    int xcd = blockIdx.x & 7;
    int s = xcd >> 1;                            // slice for this XCD pair
    int worker = (blockIdx.x >> 3) * 2 + (xcd & 1);   // 0..511 within slice
    int wave = threadIdx.x >> 6, lane = threadIdx.x & 63;
    int grp = lane >> 2, sub = lane & 3;         // 16 nodes/wave, 4 lanes/node
    size_t sbase = (size_t)s * n * 4;            // uint4 units to slice start
    const uint4* __restrict__ h4s = (const uint4*)hs + sbase;   // uniform base
    uint4* __restrict__ y4s = (uint4*)ys + sbase;
    // zero row, relative to h4s: absolute idx NSLICE*n*4 - sbase, + lane slot
    unsigned zoff = (unsigned)(NSLICE - s) * (unsigned)n * 4u + (unsigned)sub;

    for (int chunk = worker; chunk < nchunks; chunk += 512) {
        int n0 = chunk * 64 + wave * 16 + grp;
        bool valid = n0 < n;
        int node = valid ? n0 : 0;
        int d = valid ? deg[node] : 0;
        if (d > CAP) d = CAP;                    // poison-replay safe clamp
        const unsigned short* brow = bucket + (size_t)node * CAP;

        // coalesced index prefetch: lane sub holds entries sub*8..sub*8+7
        uint4 iv = *(const uint4*)&brow[sub * 8];

        // self slice (issue early; consumed at the end)
        uint4 sv = h4s[(unsigned)node * 4u + sub];

        // wave-wide max degree (uniform loop bound; per-group predication)
        int dmax = d;
        dmax = max(dmax, __shfl_xor(dmax, 4));
        dmax = max(dmax, __shfl_xor(dmax, 8));
        dmax = max(dmax, __shfl_xor(dmax, 16));
        dmax = max(dmax, __shfl_xor(dmax, 32));

        float acc[8] = {0.f,0.f,0.f,0.f,0.f,0.f,0.f,0.f};

        int dcap = dmax < 32 ? dmax : 32;        // prefix held in registers
        for (int t = 0; t < dcap; t += 8) {
            int src = (grp << 2) + (t >> 3);     // lane holding entries t..t+7
            unsigned q0 = (unsigned)__shfl((int)iv.x, src);
            unsigned q1 = (unsigned)__shfl((int)iv.y, src);
            unsigned q2 = (unsigned)__shfl((int)iv.z, src);
            unsigned q3 = (unsigned)__shfl((int)iv.w, src);
            unsigned id[8];
            id[0] = q0 & 0xffffu; id[1] = q0 >> 16;
            id[2] = q1 & 0xffffu; id[3] = q1 >> 16;
            id[4] = q2 & 0xffffu; id[5] = q2 >> 16;
            id[6] = q3 & 0xffffu; id[7] = q3 >> 16;
            // unconditional gathers; masked lanes read the zero row
            uint4 w[8];
            #pragma unroll
            for (int u = 0; u < 8; ++u) {
                unsigned off = id[u] * 4u + (unsigned)sub;   // v_lshl_add_u32
                if (t + u >= d) off = zoff;                  // 1 cndmask
                w[u] = h4s[off];                             // saddr 32-bit load
            }
            // accumulate unconditionally (zero row adds 0)
            #pragma unroll
            for (int u = 0; u < 8; ++u) {
                uint4 v = w[u];
                acc[0] += bf_lo(v.x); acc[1] += bf_hi(v.x);
                acc[2] += bf_lo(v.y); acc[3] += bf_hi(v.y);
                acc[4] += bf_lo(v.z); acc[5] += bf_hi(v.z);
                acc[6] += bf_lo(v.w); acc[7] += bf_hi(v.w);
            }
        }
        // rare tail: deg > 32 (P ~ 2e-4 per node)
        for (int e = 32; e < d; ++e) {
            unsigned idx = (unsigned)brow[e];
            uint4 v = h4s[idx * 4u + (unsigned)sub];
            acc[0] += bf_lo(v.x); acc[1] += bf_hi(v.x);
            acc[2] += bf_lo(v.y); acc[3] += bf_hi(v.y);
            acc[4] += bf_lo(v.z); acc[5] += bf_hi(v.z);
            acc[6] += bf_lo(v.w); acc[7] += bf_hi(v.w);
        }

        // add self
        acc[0] += bf_lo(sv.x); acc[1] += bf_hi(sv.x);
        acc[2] += bf_lo(sv.y); acc[3] += bf_hi(sv.y);
        acc[4] += bf_lo(sv.z); acc[5] += bf_hi(sv.z);
        acc[6] += bf_lo(sv.w); acc[7] += bf_hi(sv.w);

        if (valid) {
            uint4 o;
            o.x = (unsigned)f2bf(acc[0]) | ((unsigned)f2bf(acc[1]) << 16);
            o.y = (unsigned)f2bf(acc[2]) | ((unsigned)f2bf(acc[3]) << 16);
            o.z = (unsigned)f2bf(acc[4]) | ((unsigned)f2bf(acc[5]) << 16);
            o.w = (unsigned)f2bf(acc[6]) | ((unsigned)f2bf(acc[7]) << 16);
            y4s[(unsigned)node * 4u + sub] = o;   // 1KB/wave contiguous
        }
    }
}

// ---------------------------------------------------------------------------
// Fused layer GEMM v2 (r23, best known): 64-row tile, 3 barriers, 32x32x16
// MFMA. Wave layout: stripe = wave&1 (32 rows), nhalf = wave>>1 (64 cols);
// per GEMM per wave: 8 ksteps x (1 A-read + 2 B-reads + 2 MFMA) = 24
// ds_read. C/D layout (HW-verified): col = lane&31,
// row = (reg&3) + 8*(reg>>2) + 4*(lane>>5).
// A and outh are slice-major [NSLICE][N][32]. batch staged via LDS.
// Pooling: per-lane reg scan + shfl_xor(32); 1 atomic per col per graph.
// ---------------------------------------------------------------------------
__global__ __launch_bounds__(256) void layer_fused(const unsigned short* __restrict__ A,
                                                   const unsigned short* __restrict__ Wt1,
                                                   const unsigned short* __restrict__ Wt2,
                                                   const float* __restrict__ ea1,
                                                   const float* __restrict__ eb1,
                                                   const float* __restrict__ ea2,
                                                   const float* __restrict__ eb2,
                                                   const int* __restrict__ batch,
                                                   float* __restrict__ pooled, int loff,
                                                   unsigned short* __restrict__ outh, int n) {
    __shared__ unsigned short As[64][136];
    __shared__ unsigned short Ws[128][136];
    __shared__ int bsh[64];
    int tid = threadIdx.x;
    int row0 = blockIdx.x * 64;
    int wave = tid >> 6, lane = tid & 63;
    int stripe = wave & 1;                 // 32-row stripe within the tile
    int nhalf = wave >> 1;                 // 64-col half
    int lc = lane & 31;                    // A-row / B-col within 32-tile
    int lh = lane >> 5;                    // k-half / C-row offset

    #pragma unroll
    for (int i = 0; i < 4; ++i) {
        int idx = tid + i * 256;
        int r = idx >> 4, c = (idx & 15) * 8;
        int sl = c >> 5, off = c & 31;
        ushort8 v = (ushort8)0;
        if (row0 + r < n)
            v = *(const ushort8*)&A[((size_t)sl * n + (row0 + r)) * 32 + off];
        *(ushort8*)&As[r][c] = v;
    }
    #pragma unroll
    for (int i = 0; i < 8; ++i) {
        int idx = tid + i * 256;
        int r = idx >> 4, c = (idx & 15) * 8;
        *(ushort8*)&Ws[r][c] = *(const ushort8*)&Wt1[(size_t)r * D_FEAT + c];
    }

    ushort8 w2reg[8];
    #pragma unroll
    for (int i = 0; i < 8; ++i) {
        int idx = tid + i * 256;
        int r = idx >> 4, c = (idx & 15) * 8;
        w2reg[i] = *(const ushort8*)&Wt2[(size_t)r * D_FEAT + c];
    }

    if (tid < 64)
        bsh[tid] = (row0 + tid < n) ? batch[row0 + tid] : -1;
    __syncthreads();

    // ---- GEMM 1 (32x32x16) ----
    f32x16 acc[2] = {};
    #pragma unroll
    for (int t = 0; t < 8; ++t) {
        bf16x8 a = *(const bf16x8*)&As[stripe * 32 + lc][t * 16 + lh * 8];
        #pragma unroll
        for (int nt = 0; nt < 2; ++nt) {
            bf16x8 b = *(const bf16x8*)&Ws[nhalf * 64 + nt * 32 + lc][t * 16 + lh * 8];
            acc[nt] = __builtin_amdgcn_mfma_f32_32x32x16_bf16(a, b, acc[nt], 0, 0, 0);
        }
    }
    __syncthreads();

    // epilogue 1 -> z (bf16) into As; restore Ws = Wt2 from registers
    #pragma unroll
    for (int nt = 0; nt < 2; ++nt) {
        int col = nhalf * 64 + nt * 32 + lc;
        float al = ea1[col], be = eb1[col];
        #pragma unroll
        for (int reg = 0; reg < 16; ++reg) {
            int rr = (reg & 3) + 8 * (reg >> 2) + 4 * lh;
            float v = fmaxf(fmaf(acc[nt][reg], al, be), 0.f);
            As[stripe * 32 + rr][col] = f2bf(v);
        }
    }
    #pragma unroll
    for (int i = 0; i < 8; ++i) {
        int idx = tid + i * 256;
        int r = idx >> 4, c = (idx & 15) * 8;
        *(ushort8*)&Ws[r][c] = w2reg[i];
    }
    __syncthreads();

    // ---- GEMM 2 (32x32x16) ----
    f32x16 acc2[2] = {};
    #pragma unroll
    for (int t = 0; t < 8; ++t) {
        bf16x8 a = *(const bf16x8*)&As[stripe * 32 + lc][t * 16 + lh * 8];
        #pragma unroll
        for (int nt = 0; nt < 2; ++nt) {
            bf16x8 b = *(const bf16x8*)&Ws[nhalf * 64 + nt * 32 + lc][t * 16 + lh * 8];
            acc2[nt] = __builtin_amdgcn_mfma_f32_32x32x16_bf16(a, b, acc2[nt], 0, 0, 0);
        }
    }

    // per-lane graph ids for its 16 rows (depends only on lh, reg)
    int bq[16];
    #pragma unroll
    for (int reg = 0; reg < 16; ++reg)
        bq[reg] = bsh[stripe * 32 + (reg & 3) + 8 * (reg >> 2) + 4 * lh];

    // epilogue 2: bf16-rounded h once; global write + pooling values
    float vv[2][16];
    #pragma unroll
    for (int nt = 0; nt < 2; ++nt) {
        int col = nhalf * 64 + nt * 32 + lc;
        float al = ea2[col], be = eb2[col];
        int sl = col >> 5, off = col & 31;
        #pragma unroll
        for (int reg = 0; reg < 16; ++reg) {
            int rr = (reg & 3) + 8 * (reg >> 2) + 4 * lh;
            unsigned short hb = f2bf(fmaxf(fmaf(acc2[nt][reg], al, be), 0.f));
            vv[nt][reg] = bf2f(hb);
            if (outh) {
                int grow = row0 + stripe * 32 + rr;
                if (grow < n)
                    outh[((size_t)sl * n + grow) * 32 + off] = hb;
            }
        }
    }

    // wave pooling: rows span contiguous graphs [gmn,gmx] (batch sorted)
    int gmn = 0x7fffffff, gmx = -1;
    #pragma unroll
    for (int reg = 0; reg < 16; ++reg) {
        int bb = bq[reg];
        if (bb >= 0) {
            gmn = bb < gmn ? bb : gmn;
            gmx = bb > gmx ? bb : gmx;
        }
    }
    {
        int t;
        t = __shfl_xor(gmn, 32); gmn = t < gmn ? t : gmn;
        t = __shfl_xor(gmx, 32); gmx = t > gmx ? t : gmx;
    }
    for (int seg = gmn; seg <= gmx; ++seg) {
        #pragma unroll
        for (int nt = 0; nt < 2; ++nt) {
            float s = 0.f;
            #pragma unroll
            for (int reg = 0; reg < 16; ++reg)
                if (bq[reg] == seg) s += vv[nt][reg];
            s += __shfl_xor(s, 32);
            if (lh == 0 && s != 0.f)
                atomicAdd(&pooled[(size_t)seg * POOL_DIM + loff +
                                  nhalf * 64 + nt * 32 + lc], s);
        }
    }
}

// ---------------------------------------------------------------------------
// Fused MLP head: 128 blocks x 384 threads, 4 graphs/block. fc1 (coalesced
// W1, graphs in registers, k ascending) -> f1 in LDS -> fc2 by threads 0..39.
// ---------------------------------------------------------------------------
__global__ __launch_bounds__(384) void head_kernel(const float* __restrict__ pooled,
                                                   const float* __restrict__ W1,
                                                   const float* __restrict__ b1v,
                                                   const float* __restrict__ W2,
                                                   const float* __restrict__ b2v,
                                                   float* __restrict__ out) {
    __shared__ float f1[4][POOL_DIM];
    int j = threadIdx.x;                   // 0..383
    int g0 = blockIdx.x * 4;
    const float* pr = pooled + (size_t)g0 * POOL_DIM;
    float bb = b1v[j];
    float s0 = bb, s1 = bb, s2 = bb, s3 = bb;
    for (int k0 = 0; k0 < POOL_DIM; k0 += 8) {
        float w[8];
        #pragma unroll
        for (int i = 0; i < 8; ++i)
            w[i] = W1[(size_t)(k0 + i) * POOL_DIM + j];
        #pragma unroll
        for (int i = 0; i < 8; ++i) {
            int k = k0 + i;
            s0 = fmaf(pr[k],                w[i], s0);
            s1 = fmaf(pr[POOL_DIM + k],     w[i], s1);
            s2 = fmaf(pr[2 * POOL_DIM + k], w[i], s2);
            s3 = fmaf(pr[3 * POOL_DIM + k], w[i], s3);
        }
    }
    f1[0][j] = fmaxf(s0, 0.f);
    f1[1][j] = fmaxf(s1, 0.f);
    f1[2][j] = fmaxf(s2, 0.f);
    f1[3][j] = fmaxf(s3, 0.f);
    __syncthreads();
    if (j < 4 * N_CLASSES) {
        int g = j / N_CLASSES, c = j % N_CLASSES;
        float s = b2v[c];
        for (int k = 0; k < POOL_DIM; ++k)
            s = fmaf(f1[g][k], W2[(size_t)k * N_CLASSES + c], s);
        out[(size_t)(g0 + g) * N_CLASSES + c] = s;
    }
}

// ---------------------------------------------------------------------------
extern "C" void kernel_launch(void* const* d_in, const int* in_sizes, int n_in,
                              void* d_out, int out_size, void* d_ws, size_t ws_size,
                              hipStream_t stream) {
    const float* x      = (const float*)d_in[0];
    const int*   ei     = (const int*)  d_in[1];
    const int*   batch  = (const int*)  d_in[2];
    const float* W1     = (const float*)d_in[3];
    const float* b1     = (const float*)d_in[4];
    const float* gamma  = (const float*)d_in[5];
    const float* beta   = (const float*)d_in[6];
    const float* rm     = (const float*)d_in[7];
    const float* rv     = (const float*)d_in[8];
    const float* W2     = (const float*)d_in[9];
    const float* b2     = (const float*)d_in[10];
    const float* lin1W  = (const float*)d_in[11];
    const float* lin1b  = (const float*)d_in[12];
    const float* lin2W  = (const float*)d_in[13];
    const float* lin2b  = (const float*)d_in[14];
    float* out = (float*)d_out;

    const int N = in_sizes[0] / D_FEAT;   // 50000
    const int E = in_sizes[1] / 2;        // 800000

    char* ws = (char*)d_ws;
    auto carve = [&](size_t bytes) {
        char* p = ws;
        ws += (bytes + 255) & ~(size_t)255;
        return p;
    };
    int*   cursor    = (int*)  carve((size_t)N * 4);
    int*   cnts      = (int*)  carve((size_t)NBINS * 256 * 4);
    unsigned short* bucket = (unsigned short*)carve((size_t)N * CAP * 2);
    int2*  pairs     = (int2*) carve((size_t)NBINS * 256 * SLABCAP * 8);
    float* ea        = (float*)carve((size_t)2 * N_LAYERS * D_FEAT * 4);
    float* eb        = (float*)carve((size_t)2 * N_LAYERS * D_FEAT * 4);
    unsigned short* Wt   = (unsigned short*)carve((size_t)2 * N_LAYERS * D_FEAT * D_FEAT * 2);
    unsigned short* xb   = (unsigned short*)carve((size_t)N * D_FEAT * 2 + 64);   // +64B zero row
    unsigned short* ybuf = (unsigned short*)carve((size_t)N * D_FEAT * 2);
    unsigned short* hbuf = (unsigned short*)carve((size_t)N * D_FEAT * 2 + 64);   // +64B zero row
    float* pooled    = (float*)carve((size_t)N_GRAPHS * POOL_DIM * 4);

    // merged setup grid layout
    const int n4 = N * D_FEAT / 4;
    const int B0 = (n4 + 255) / 256;                            // cvt_x
    const int B1 = B0 + 24;                                     // cvt_w: 6 slots x 4 tiles
    const int B2 = B1 + 2;                                      // prep (+tail zero)
    const int B3 = B2 + (N + 255) / 256;                        // cursor zero
    const int B4 = B3 + (N_GRAPHS * POOL_DIM + 255) / 256;      // pooled zero
    const int B5 = B4 + 256;                                    // bin

    setup_kernel<<<B5, 256, 0, stream>>>(x, xb, hbuf, W1, W2, Wt, b1, gamma,
                                         beta, rm, rv, b2, ea, eb, cursor,
                                         pooled, ei, pairs, cnts, E,
                                         N, n4, B0, B1, B2, B3, B4);
    fill_v3<<<8 * 64, 256, 0, stream>>>(pairs, cnts, cursor, bucket);

    const int nchunks = (N + 63) / 64;              // 64 nodes per chunk

    const unsigned short* hprev = xb;
    for (int l = 0; l < N_LAYERS; ++l) {
        agg_slice<<<2048, 256, 0, stream>>>(hprev, cursor, bucket, ybuf,
                                            N, nchunks);
        unsigned short* outh = (l == N_LAYERS - 1) ? nullptr : hbuf;
        layer_fused<<<(N + 63) / 64, 256, 0, stream>>>(ybuf,
                      Wt + (size_t)(2 * l) * D_FEAT * D_FEAT,
                      Wt + (size_t)(2 * l + 1) * D_FEAT * D_FEAT,
                      ea + (size_t)(2 * l) * D_FEAT,
                      eb + (size_t)(2 * l) * D_FEAT,
                      ea + (size_t)(2 * l + 1) * D_FEAT,
                      eb + (size_t)(2 * l + 1) * D_FEAT,
                      batch, pooled, l * D_FEAT, outh, N);
        hprev = hbuf;
    }
    head_kernel<<<N_GRAPHS / 4, 384, 0, stream>>>(pooled, lin1W, lin1b, lin2W, lin2b, out);
}